// Round 9
// baseline (796.896 us; speedup 1.0000x reference)
//
#include <hip/hip_runtime.h>
#include <math.h>

#define P 512
#define KC 10
#define NB 32
#define EPSV 0.01f
#define XT 17024   // padded columns: 16384 + per-class 64-alignment

typedef __attribute__((ext_vector_type(8))) __bf16 bf16x8;
typedef __attribute__((ext_vector_type(4))) float floatx4;

// swizzled LDS panel element index for (row t, col c in [0,32))
__device__ __forceinline__ int pad_(int t, int c){
  return (t * 4 + ((c >> 3) ^ ((t >> 1) & 3))) * 8 + (c & 7);
}

// ---------------- fused histogram + padded offsets + colmap scatter (one block) ----------------
__global__ __launch_bounds__(256) void sort_k(const int* __restrict__ Y, int* __restrict__ colmap,
                                              int* __restrict__ counts, int* __restrict__ off_pad,
                                              int* __restrict__ done, int m){
  __shared__ int cnt[KC], offp[KC + 1], cur[KC];
  int tid = threadIdx.x;
  if (tid == 0) *done = 0;
  if (tid < KC) cnt[tid] = 0;
  __syncthreads();
  for (int i = tid; i < m; i += 256){
    int y = Y[i];
    if (y >= 0 && y < KC) atomicAdd(&cnt[y], 1);
  }
  __syncthreads();
  if (tid == 0){
    int s = 0;
    for (int j = 0; j < KC; ++j){ offp[j] = s; s += ((cnt[j] + 63) >> 6) << 6; }
    offp[KC] = s;
  }
  __syncthreads();
  if (tid < KC){ cur[tid] = offp[tid]; counts[tid] = cnt[tid]; off_pad[tid] = offp[tid]; }
  if (tid == KC) off_pad[KC] = offp[KC];
  for (int i = tid; i < XT; i += 256) colmap[i] = -1;
  __syncthreads();
  for (int i = tid; i < m; i += 256){
    int y = Y[i];
    if (y >= 0 && y < KC){
      int pos = atomicAdd(&cur[y], 1);
      colmap[pos] = i;
    }
  }
}

// ---------------- transpose + split-bf16 convert: X[m][512] -> Xt_hi/lo[512][XT] ----------------
__global__ __launch_bounds__(256) void xt_k(const float* __restrict__ X, const int* __restrict__ colmap,
                                            __bf16* __restrict__ Xhi, __bf16* __restrict__ Xlo){
  __shared__ float T[64][65];
  int c0 = blockIdx.x * 64;
  int f0 = blockIdx.y * 64;
  int tid = threadIdx.x;

  int j = tid >> 2;
  int piece = tid & 3;
  int s = colmap[c0 + j];
  if (s >= 0){
    const float* src = X + (long)s * P + f0 + piece * 16;
    #pragma unroll
    for (int q = 0; q < 4; ++q){
      float4 v = *(const float4*)(src + q * 4);
      T[piece * 16 + q * 4 + 0][j] = v.x;
      T[piece * 16 + q * 4 + 1][j] = v.y;
      T[piece * 16 + q * 4 + 2][j] = v.z;
      T[piece * 16 + q * 4 + 3][j] = v.w;
    }
  } else {
    #pragma unroll
    for (int q = 0; q < 16; ++q) T[piece * 16 + q][j] = 0.f;
  }
  __syncthreads();

  int f = tid >> 2;
  int cp = (tid & 3) * 16;
  bf16x8 vh0, vl0, vh1, vl1;
  #pragma unroll
  for (int q = 0; q < 8; ++q){
    float x0 = T[f][cp + q];
    float x1 = T[f][cp + 8 + q];
    __bf16 h0 = (__bf16)x0, h1 = (__bf16)x1;
    vh0[q] = h0; vl0[q] = (__bf16)(x0 - (float)h0);
    vh1[q] = h1; vl1[q] = (__bf16)(x1 - (float)h1);
  }
  long base = (long)(f0 + f) * XT + c0 + cp;
  *(bf16x8*)&Xhi[base]     = vh0;
  *(bf16x8*)&Xhi[base + 8] = vh1;
  *(bf16x8*)&Xlo[base]     = vl0;
  *(bf16x8*)&Xlo[base + 8] = vl1;
}

// ---------------- per-class Gram via MFMA, split-bf16 ----------------
__global__ __launch_bounds__(256) void gram_mfma(const __bf16* __restrict__ Xhi,
                                                 const __bf16* __restrict__ Xlo,
                                                 const int* __restrict__ counts,
                                                 const int* __restrict__ off_pad,
                                                 float* __restrict__ Gk){
  int cls = blockIdx.y;
  int ta = 0, rem = blockIdx.x;
  while (rem >= ta + 1){ rem -= ta + 1; ++ta; }
  int tb = rem;
  int a0 = ta * 64, b0 = tb * 64;

  int tid  = threadIdx.x;
  int lane = tid & 63;
  int wv   = tid >> 6;
  int wrow = wv >> 1, wcol = wv & 1;
  int fr   = lane & 15;
  int quad = lane >> 4;

  int cs0     = off_pad[cls];
  int nchunks = (counts[cls] + 31) >> 5;

  long arow0 = (long)(a0 + wrow * 32 + fr) * XT;
  long brow0 = (long)(b0 + wcol * 32 + fr) * XT;

  floatx4 acc[2][2];
  #pragma unroll
  for (int i = 0; i < 2; ++i)
    #pragma unroll
    for (int j = 0; j < 2; ++j) acc[i][j] = (floatx4){0.f, 0.f, 0.f, 0.f};

  for (int ch = 0; ch < nchunks; ++ch){
    long co = cs0 + ch * 32 + quad * 8;
    bf16x8 ah[2], al[2], bh[2], bl[2];
    #pragma unroll
    for (int r = 0; r < 2; ++r){
      ah[r] = *(const bf16x8*)&Xhi[arow0 + (long)r * 16 * XT + co];
      al[r] = *(const bf16x8*)&Xlo[arow0 + (long)r * 16 * XT + co];
      bh[r] = *(const bf16x8*)&Xhi[brow0 + (long)r * 16 * XT + co];
      bl[r] = *(const bf16x8*)&Xlo[brow0 + (long)r * 16 * XT + co];
    }
    #pragma unroll
    for (int ri = 0; ri < 2; ++ri)
      #pragma unroll
      for (int rj = 0; rj < 2; ++rj){
        acc[ri][rj] = __builtin_amdgcn_mfma_f32_16x16x32_bf16(al[ri], bh[rj], acc[ri][rj], 0, 0, 0);
        acc[ri][rj] = __builtin_amdgcn_mfma_f32_16x16x32_bf16(ah[ri], bl[rj], acc[ri][rj], 0, 0, 0);
        acc[ri][rj] = __builtin_amdgcn_mfma_f32_16x16x32_bf16(ah[ri], bh[rj], acc[ri][rj], 0, 0, 0);
      }
  }

  float* C = Gk + (long)cls * P * P;
  #pragma unroll
  for (int ri = 0; ri < 2; ++ri){
    int a = a0 + wrow * 32 + ri * 16 + (lane >> 4) * 4;
    #pragma unroll
    for (int rj = 0; rj < 2; ++rj){
      int b = b0 + wcol * 32 + rj * 16 + (lane & 15);
      #pragma unroll
      for (int r = 0; r < 4; ++r)
        C[(long)(a + r) * P + b] = acc[ri][rj][r];
    }
  }
}

// ---------------- slot 10 = sum of class Grams ----------------
__global__ __launch_bounds__(256) void sum10_k(float* __restrict__ Gk){
  long i = (long)blockIdx.x * 256 + threadIdx.x;
  float4 s = {0.f, 0.f, 0.f, 0.f};
  #pragma unroll
  for (int j = 0; j < KC; ++j){
    float4 v = ((const float4*)(Gk + (long)j * P * P))[i];
    s.x += v.x; s.y += v.y; s.z += v.z; s.w += v.w;
  }
  ((float4*)(Gk + (long)KC * P * P))[i] = s;
}

// ---------------- LEFT-LOOKING MFMA Cholesky logdet ----------------
// 11 blocks x 1024 threads. Per 32-col panel step s (j0=32s):
//  P1: panel = sc*G(+I) - Lhist[j0:,0:j0] @ Lhist[j0:j0+32,0:j0]^T  (deep-K MFMA GEMM,
//      reads write-once split-bf16 Lg; no trailing RMW at all), staged to LDS (bf16 hi/lo)
//      + fp32 diag block in Dd.
//  P2: wave 0 factors 32x32 diag (shfl, registers) + builds Minv=L11^-1 + pivot logs.
//  P3: L21 = Pan @ Minv^T via MFMA; write-once to Lg (global, bf16 hi/lo).
// G stays pristine. Last-finished block computes outputs (done counter).
__global__ __launch_bounds__(1024) void chol_left(const float* __restrict__ Gk,
                                                  __bf16* __restrict__ Lghi,
                                                  __bf16* __restrict__ Lglo,
                                                  const int* __restrict__ counts,
                                                  float* __restrict__ logdets,
                                                  int* __restrict__ done,
                                                  float* __restrict__ out,
                                                  float m_tot){
  __shared__ __bf16 Phi[P * NB];      // 32 KB  panel hi (swizzled)
  __shared__ __bf16 Plo[P * NB];      // 32 KB  panel lo
  __shared__ float  Dd[NB * 33];      // fp32 diag block
  __shared__ float  Ld[NB * 33];      // factored L11 rows
  __shared__ float  Ldr[NB];          // 1/diag
  __shared__ float  Minv[NB * 36];    // L11^-1 (row-major, stride 36)

  int mat  = blockIdx.x;
  int tid  = threadIdx.x;
  int lane = tid & 63;
  int wv   = tid >> 6;
  int quad = lane >> 4;
  int fr   = lane & 15;
  const float* A = Gk + (long)mat * P * P;
  long lb = (long)mat * P * P;
  float sc = (mat < KC) ? ((float)P / (((float)counts[mat] + 1e-8f) * EPSV))
                        : ((float)P / (m_tot * EPSV));
  float logsum = 0.f;

  for (int s = 0; s < 16; ++s){
    int j0 = s * NB;
    int q  = P - j0;

    // ==== phase 1: deep-K GEMM update + transform -> LDS panel ====
    int nt = q >> 4;                    // 16-row tiles
    for (int rt = wv; rt < nt; rt += 16){
      int g0 = j0 + rt * 16;
      floatx4 acc[2] = {{0.f,0.f,0.f,0.f},{0.f,0.f,0.f,0.f}};
      for (int ch = 0; ch < s; ++ch){
        long co = (long)ch * 32 + quad * 8;
        bf16x8 ah = *(const bf16x8*)&Lghi[lb + (long)(g0 + fr) * P + co];
        bf16x8 al = *(const bf16x8*)&Lglo[lb + (long)(g0 + fr) * P + co];
        #pragma unroll
        for (int h2 = 0; h2 < 2; ++h2){
          bf16x8 bh = *(const bf16x8*)&Lghi[lb + (long)(j0 + h2 * 16 + fr) * P + co];
          bf16x8 bl = *(const bf16x8*)&Lglo[lb + (long)(j0 + h2 * 16 + fr) * P + co];
          acc[h2] = __builtin_amdgcn_mfma_f32_16x16x32_bf16(al, bh, acc[h2], 0, 0, 0);
          acc[h2] = __builtin_amdgcn_mfma_f32_16x16x32_bf16(ah, bl, acc[h2], 0, 0, 0);
          acc[h2] = __builtin_amdgcn_mfma_f32_16x16x32_bf16(ah, bh, acc[h2], 0, 0, 0);
        }
      }
      // transform + stage:  C/D layout: col=fr (B-row), row=quad*4+r (A-row)
      #pragma unroll
      for (int h2 = 0; h2 < 2; ++h2){
        #pragma unroll
        for (int r = 0; r < 4; ++r){
          int grow = g0 + quad * 4 + r;
          int gcol = j0 + h2 * 16 + fr;
          float v = sc * A[(long)grow * P + gcol] + ((grow == gcol) ? 1.f : 0.f) - acc[h2][r];
          int t = rt * 16 + quad * 4 + r;
          int c = h2 * 16 + fr;
          __bf16 hh = (__bf16)v;
          int ad = pad_(t, c);
          Phi[ad] = hh;
          Plo[ad] = (__bf16)(v - (float)hh);
          if (t < NB) Dd[t * 33 + c] = v;
        }
      }
    }
    __syncthreads();

    // ==== phase 2: wave 0 diag factor + Minv + pivot logs ====
    if (wv == 0){
      float a[NB];
      float myp = 1.f;
      if (lane < NB){
        #pragma unroll
        for (int u = 0; u < NB; ++u) a[u] = Dd[lane * 33 + u];
      } else {
        #pragma unroll
        for (int u = 0; u < NB; ++u) a[u] = 0.f;
      }
      #pragma unroll
      for (int jj = 0; jj < NB; ++jj){
        float d = __shfl(a[jj], jj);
        if (lane == jj) myp = d;
        float inv = 1.0f / d;
        float rs  = rsqrtf(d);
        float w   = a[jj] * inv;
        #pragma unroll
        for (int l = jj + 1; l < NB; ++l){
          float prl = __shfl(a[l], jj);
          if (lane > jj) a[l] -= w * prl;
        }
        if (lane >= jj) a[jj] *= rs;
      }
      if (lane < NB){
        #pragma unroll
        for (int u = 0; u < NB; ++u) Ld[lane * 33 + u] = a[u];
        Ldr[lane] = 1.0f / a[lane];
      }
      if (lane < NB){
        float x[NB];
        #pragma unroll
        for (int r2 = 0; r2 < NB; ++r2){
          float acc2 = (r2 == lane) ? 1.f : 0.f;
          #pragma unroll
          for (int u = 0; u < r2; ++u)
            acc2 -= Ld[r2 * 33 + u] * x[u];
          x[r2] = acc2 * Ldr[r2];
        }
        #pragma unroll
        for (int r2 = 0; r2 < NB; ++r2) Minv[r2 * 36 + lane] = x[r2];
      }
      float lp = (lane < NB) ? logf(myp) : 0.f;
      #pragma unroll
      for (int off = 16; off >= 1; off >>= 1) lp += __shfl_xor(lp, off);
      if (tid == 0) logsum += lp;
    }
    __syncthreads();

    // ==== phase 3: trsm L21 = Pan[32:q] @ Minv^T (MFMA), write-once to Lg ====
    if (q > NB){
      bf16x8 mh[2], ml[2];
      #pragma unroll
      for (int h2 = 0; h2 < 2; ++h2){
        const float* mp = &Minv[(h2 * 16 + fr) * 36 + quad * 8];
        float4 m0 = *(const float4*)mp;
        float4 m1 = *(const float4*)(mp + 4);
        float mv[8] = {m0.x, m0.y, m0.z, m0.w, m1.x, m1.y, m1.z, m1.w};
        #pragma unroll
        for (int u = 0; u < 8; ++u){
          __bf16 h = (__bf16)mv[u];
          mh[h2][u] = h; ml[h2][u] = (__bf16)(mv[u] - (float)h);
        }
      }
      int nt3 = (q - NB) >> 4;
      for (int rt = wv; rt < nt3; rt += 16){
        int t0 = NB + rt * 16;
        int ad = pad_(t0 + fr, quad * 8);
        bf16x8 ah = *(const bf16x8*)&Phi[ad];
        bf16x8 al = *(const bf16x8*)&Plo[ad];
        #pragma unroll
        for (int h2 = 0; h2 < 2; ++h2){
          floatx4 acc = {0.f, 0.f, 0.f, 0.f};
          acc = __builtin_amdgcn_mfma_f32_16x16x32_bf16(al, mh[h2], acc, 0, 0, 0);
          acc = __builtin_amdgcn_mfma_f32_16x16x32_bf16(ah, ml[h2], acc, 0, 0, 0);
          acc = __builtin_amdgcn_mfma_f32_16x16x32_bf16(ah, mh[h2], acc, 0, 0, 0);
          #pragma unroll
          for (int r = 0; r < 4; ++r){
            int g   = j0 + t0 + quad * 4 + r;
            int col = j0 + h2 * 16 + fr;
            float y = acc[r];
            __bf16 hh = (__bf16)y;
            long go = lb + (long)g * P + col;
            Lghi[go] = hh;
            Lglo[go] = (__bf16)(y - (float)hh);
          }
        }
      }
    }
    __syncthreads();   // drains Lg writes (vmcnt0 before barrier); WAR on Phi/Plo
  }

  // ==== epilogue: publish logdet; last block computes outputs ====
  if (tid == 0){
    __hip_atomic_store(&logdets[mat], logsum, __ATOMIC_RELEASE, __HIP_MEMORY_SCOPE_AGENT);
    int old = __hip_atomic_fetch_add(done, 1, __ATOMIC_ACQ_REL, __HIP_MEMORY_SCOPE_AGENT);
    if (old == KC){
      float ld[KC + 1];
      #pragma unroll
      for (int j = 0; j <= KC; ++j)
        ld[j] = __hip_atomic_load(&logdets[j], __ATOMIC_ACQUIRE, __HIP_MEMORY_SCOPE_AGENT);
      out[0] = 0.5f * ld[KC];
      float comp = 0.f;
      for (int j = 0; j < KC; ++j){
        float trPi = (float)counts[j] + 1e-8f;
        comp += ld[j] * trPi / m_tot;
      }
      out[1] = 0.5f * comp;
    }
  }
}

extern "C" void kernel_launch(void* const* d_in, const int* in_sizes, int n_in,
                              void* d_out, int out_size, void* d_ws, size_t ws_size,
                              hipStream_t stream) {
  (void)n_in; (void)out_size; (void)ws_size;
  const float* X = (const float*)d_in[0];
  const int*   Y = (const int*)d_in[1];
  int m = in_sizes[0] / P;     // 16384

  float*  Gk      = (float*)d_ws;                    // 11 * P*P floats
  __bf16* Xhi     = (__bf16*)(Gk + 11L * P * P);     // 512*XT bf16
  __bf16* Xlo     = Xhi + (long)P * XT;              // 512*XT bf16
  int*    colmap  = (int*)(Xlo + (long)P * XT);      // XT ints
  int*    counts  = colmap + XT;                     // 16
  int*    off_pad = counts + 16;                     // 17
  int*    done    = off_pad + 17;                    // 1
  float*  logdets = (float*)(done + 1);              // 16

  // L planes alias the X planes (dead after gram_mfma); 11*P*P <= P*XT
  __bf16* Lghi = Xhi;
  __bf16* Lglo = Xlo;

  sort_k<<<1, 256, 0, stream>>>(Y, colmap, counts, off_pad, done, m);

  dim3 xg(XT / 64, 8);
  xt_k<<<xg, 256, 0, stream>>>(X, colmap, Xhi, Xlo);

  dim3 gg(36, KC);
  gram_mfma<<<gg, 256, 0, stream>>>(Xhi, Xlo, counts, off_pad, Gk);

  sum10_k<<<P * P / 1024, 256, 0, stream>>>(Gk);

  chol_left<<<KC + 1, 1024, 0, stream>>>(Gk, Lghi, Lglo, counts, logdets, done,
                                         (float*)d_out, (float)m);
}

// Round 10
// 638.992 us; speedup vs baseline: 1.2471x; 1.2471x over previous
//
#include <hip/hip_runtime.h>
#include <math.h>

#define P 512
#define KC 10
#define NB 32
#define EPSV 0.01f
#define XT 17024   // padded columns: 16384 + per-class 64-alignment

typedef __attribute__((ext_vector_type(8))) __bf16 bf16x8;
typedef __attribute__((ext_vector_type(4))) float floatx4;

// ---------------- fused histogram + padded offsets + colmap scatter (one block) ----------------
__global__ __launch_bounds__(256) void sort_k(const int* __restrict__ Y, int* __restrict__ colmap,
                                              int* __restrict__ counts, int* __restrict__ off_pad,
                                              int* __restrict__ done, int m){
  __shared__ int cnt[KC], offp[KC + 1], cur[KC];
  int tid = threadIdx.x;
  if (tid == 0) *done = 0;
  if (tid < KC) cnt[tid] = 0;
  __syncthreads();
  for (int i = tid; i < m; i += 256){
    int y = Y[i];
    if (y >= 0 && y < KC) atomicAdd(&cnt[y], 1);
  }
  __syncthreads();
  if (tid == 0){
    int s = 0;
    for (int j = 0; j < KC; ++j){ offp[j] = s; s += ((cnt[j] + 63) >> 6) << 6; }
    offp[KC] = s;
  }
  __syncthreads();
  if (tid < KC){ cur[tid] = offp[tid]; counts[tid] = cnt[tid]; off_pad[tid] = offp[tid]; }
  if (tid == KC) off_pad[KC] = offp[KC];
  for (int i = tid; i < XT; i += 256) colmap[i] = -1;
  __syncthreads();
  for (int i = tid; i < m; i += 256){
    int y = Y[i];
    if (y >= 0 && y < KC){
      int pos = atomicAdd(&cur[y], 1);
      colmap[pos] = i;
    }
  }
}

// ---------------- transpose + split-bf16 convert: X[m][512] -> Xt_hi/lo[512][XT] ----------------
__global__ __launch_bounds__(256) void xt_k(const float* __restrict__ X, const int* __restrict__ colmap,
                                            __bf16* __restrict__ Xhi, __bf16* __restrict__ Xlo){
  __shared__ float T[64][65];
  int c0 = blockIdx.x * 64;
  int f0 = blockIdx.y * 64;
  int tid = threadIdx.x;

  int j = tid >> 2;
  int piece = tid & 3;
  int s = colmap[c0 + j];
  if (s >= 0){
    const float* src = X + (long)s * P + f0 + piece * 16;
    #pragma unroll
    for (int q = 0; q < 4; ++q){
      float4 v = *(const float4*)(src + q * 4);
      T[piece * 16 + q * 4 + 0][j] = v.x;
      T[piece * 16 + q * 4 + 1][j] = v.y;
      T[piece * 16 + q * 4 + 2][j] = v.z;
      T[piece * 16 + q * 4 + 3][j] = v.w;
    }
  } else {
    #pragma unroll
    for (int q = 0; q < 16; ++q) T[piece * 16 + q][j] = 0.f;
  }
  __syncthreads();

  int f = tid >> 2;
  int cp = (tid & 3) * 16;
  bf16x8 vh0, vl0, vh1, vl1;
  #pragma unroll
  for (int q = 0; q < 8; ++q){
    float x0 = T[f][cp + q];
    float x1 = T[f][cp + 8 + q];
    __bf16 h0 = (__bf16)x0, h1 = (__bf16)x1;
    vh0[q] = h0; vl0[q] = (__bf16)(x0 - (float)h0);
    vh1[q] = h1; vl1[q] = (__bf16)(x1 - (float)h1);
  }
  long base = (long)(f0 + f) * XT + c0 + cp;
  *(bf16x8*)&Xhi[base]     = vh0;
  *(bf16x8*)&Xhi[base + 8] = vh1;
  *(bf16x8*)&Xlo[base]     = vl0;
  *(bf16x8*)&Xlo[base + 8] = vl1;
}

// ---------------- per-class Gram via MFMA, split-bf16 ----------------
__global__ __launch_bounds__(256) void gram_mfma(const __bf16* __restrict__ Xhi,
                                                 const __bf16* __restrict__ Xlo,
                                                 const int* __restrict__ counts,
                                                 const int* __restrict__ off_pad,
                                                 float* __restrict__ Gk){
  int cls = blockIdx.y;
  int ta = 0, rem = blockIdx.x;
  while (rem >= ta + 1){ rem -= ta + 1; ++ta; }
  int tb = rem;
  int a0 = ta * 64, b0 = tb * 64;

  int tid  = threadIdx.x;
  int lane = tid & 63;
  int wv   = tid >> 6;
  int wrow = wv >> 1, wcol = wv & 1;
  int fr   = lane & 15;
  int quad = lane >> 4;

  int cs0     = off_pad[cls];
  int nchunks = (counts[cls] + 31) >> 5;

  long arow0 = (long)(a0 + wrow * 32 + fr) * XT;
  long brow0 = (long)(b0 + wcol * 32 + fr) * XT;

  floatx4 acc[2][2];
  #pragma unroll
  for (int i = 0; i < 2; ++i)
    #pragma unroll
    for (int j = 0; j < 2; ++j) acc[i][j] = (floatx4){0.f, 0.f, 0.f, 0.f};

  for (int ch = 0; ch < nchunks; ++ch){
    long co = cs0 + ch * 32 + quad * 8;
    bf16x8 ah[2], al[2], bh[2], bl[2];
    #pragma unroll
    for (int r = 0; r < 2; ++r){
      ah[r] = *(const bf16x8*)&Xhi[arow0 + (long)r * 16 * XT + co];
      al[r] = *(const bf16x8*)&Xlo[arow0 + (long)r * 16 * XT + co];
      bh[r] = *(const bf16x8*)&Xhi[brow0 + (long)r * 16 * XT + co];
      bl[r] = *(const bf16x8*)&Xlo[brow0 + (long)r * 16 * XT + co];
    }
    #pragma unroll
    for (int ri = 0; ri < 2; ++ri)
      #pragma unroll
      for (int rj = 0; rj < 2; ++rj){
        acc[ri][rj] = __builtin_amdgcn_mfma_f32_16x16x32_bf16(al[ri], bh[rj], acc[ri][rj], 0, 0, 0);
        acc[ri][rj] = __builtin_amdgcn_mfma_f32_16x16x32_bf16(ah[ri], bl[rj], acc[ri][rj], 0, 0, 0);
        acc[ri][rj] = __builtin_amdgcn_mfma_f32_16x16x32_bf16(ah[ri], bh[rj], acc[ri][rj], 0, 0, 0);
      }
  }

  float* C = Gk + (long)cls * P * P;
  #pragma unroll
  for (int ri = 0; ri < 2; ++ri){
    int a = a0 + wrow * 32 + ri * 16 + (lane >> 4) * 4;
    #pragma unroll
    for (int rj = 0; rj < 2; ++rj){
      int b = b0 + wcol * 32 + rj * 16 + (lane & 15);
      #pragma unroll
      for (int r = 0; r < 4; ++r)
        C[(long)(a + r) * P + b] = acc[ri][rj][r];
    }
  }
}

// ---------------- slot 10 = sum of class Grams ----------------
__global__ __launch_bounds__(256) void sum10_k(float* __restrict__ Gk){
  long i = (long)blockIdx.x * 256 + threadIdx.x;
  float4 s = {0.f, 0.f, 0.f, 0.f};
  #pragma unroll
  for (int j = 0; j < KC; ++j){
    float4 v = ((const float4*)(Gk + (long)j * P * P))[i];
    s.x += v.x; s.y += v.y; s.z += v.z; s.w += v.w;
  }
  ((float4*)(Gk + (long)KC * P * P))[i] = s;
}

// ---------------- LEFT-LOOKING MFMA Cholesky, coalesced panel-block L layout ----------------
// Lg layout: per matrix (P*P elems), step ch occupies [ch*P*32, (ch+1)*P*32):
// element (row r, col c in [0,32)) at ch*P*32 + r*32 + c. All loads/stores are
// 16B/lane, wave-contiguous (1-4 KB per instruction).
// Per step s (j0=32s):
//  P1: Pan(fp32 LDS) = sc*G(+I) - Lhist @ L[j0:j0+32]^T  (deep-K split-bf16 MFMA GEMM)
//  P2: wave0 factors 32x32 diag from Pan (shfl registers), stores Ld/Ldr,
//      zeroes upper-tri, publishes L11 rows to Lg; per-lane pivot logs (off-chain)
//  P3: per-thread fp32 trsm of row j0+32+t vs Ld (R7-proven), publish row to Lg
__global__ __launch_bounds__(1024) void chol_left(const float* __restrict__ Gk,
                                                  __bf16* __restrict__ Lghi,
                                                  __bf16* __restrict__ Lglo,
                                                  const int* __restrict__ counts,
                                                  float* __restrict__ logdets,
                                                  int* __restrict__ done,
                                                  float* __restrict__ out,
                                                  float m_tot){
  __shared__ float Pan[P * 33];       // 67.6 KB fp32 panel (rows 0..q-1 of strip)
  __shared__ float Ld[NB * 33];       // factored L11 rows
  __shared__ float Ldr[NB];           // 1/diag

  int mat  = blockIdx.x;
  int tid  = threadIdx.x;
  int lane = tid & 63;
  int wv   = tid >> 6;
  int quad = lane >> 4;
  int fr   = lane & 15;
  const float* A = Gk + (long)mat * P * P;
  long lb = (long)mat * P * P;
  float sc = (mat < KC) ? ((float)P / (((float)counts[mat] + 1e-8f) * EPSV))
                        : ((float)P / (m_tot * EPSV));
  float loglocal = 0.f;   // per-lane (wave 0) pivot-log accumulator

  for (int s = 0; s < 16; ++s){
    int j0 = s * NB;
    int q  = P - j0;

    // ==== phase 1: deep-K GEMM + transform -> Pan (fp32 LDS) ====
    int nt = q >> 4;                    // 16-row tiles
    for (int rt = wv; rt < nt; rt += 16){
      int gr0 = j0 + rt * 16;
      floatx4 acc[2] = {{0.f,0.f,0.f,0.f},{0.f,0.f,0.f,0.f}};
      for (int ch = 0; ch < s; ++ch){
        long cbase = lb + (long)ch * P * NB;
        long aoff = cbase + (long)(gr0 + fr) * NB + quad * 8;
        bf16x8 ah = *(const bf16x8*)&Lghi[aoff];
        bf16x8 al = *(const bf16x8*)&Lglo[aoff];
        #pragma unroll
        for (int h2 = 0; h2 < 2; ++h2){
          long boff = cbase + (long)(j0 + h2 * 16 + fr) * NB + quad * 8;
          bf16x8 bh = *(const bf16x8*)&Lghi[boff];
          bf16x8 bl = *(const bf16x8*)&Lglo[boff];
          acc[h2] = __builtin_amdgcn_mfma_f32_16x16x32_bf16(al, bh, acc[h2], 0, 0, 0);
          acc[h2] = __builtin_amdgcn_mfma_f32_16x16x32_bf16(ah, bl, acc[h2], 0, 0, 0);
          acc[h2] = __builtin_amdgcn_mfma_f32_16x16x32_bf16(ah, bh, acc[h2], 0, 0, 0);
        }
      }
      // C/D layout (m89): D row = quad*4+reg (A's m), D col = fr (B's n)
      #pragma unroll
      for (int h2 = 0; h2 < 2; ++h2){
        #pragma unroll
        for (int r = 0; r < 4; ++r){
          int grow = gr0 + quad * 4 + r;
          int gcol = j0 + h2 * 16 + fr;
          float v = sc * A[(long)grow * P + gcol] + ((grow == gcol) ? 1.f : 0.f) - acc[h2][r];
          Pan[(grow - j0) * 33 + (gcol - j0)] = v;
        }
      }
    }
    __syncthreads();

    // ==== phase 2: wave 0 diag factor + publish L11 ====
    if (wv == 0){
      float a[NB];
      float myp = 1.f;
      if (lane < NB){
        #pragma unroll
        for (int u = 0; u < NB; ++u) a[u] = Pan[lane * 33 + u];
      } else {
        #pragma unroll
        for (int u = 0; u < NB; ++u) a[u] = 0.f;
      }
      #pragma unroll
      for (int jj = 0; jj < NB; ++jj){
        float d = __shfl(a[jj], jj);
        if (lane == jj) myp = d;
        float inv = 1.0f / d;
        float rs  = rsqrtf(d);
        float w   = a[jj] * inv;
        #pragma unroll
        for (int l = jj + 1; l < NB; ++l){
          float prl = __shfl(a[l], jj);
          if (lane > jj) a[l] -= w * prl;
        }
        if (lane >= jj) a[jj] *= rs;
      }
      if (lane < NB){
        #pragma unroll
        for (int u = 0; u < NB; ++u) Ld[lane * 33 + u] = a[u];
        Ldr[lane] = 1.0f / a[lane];
        // zero junk upper triangle before publishing (GEMM reads full rows)
        #pragma unroll
        for (int u = 0; u < NB; ++u) if (u > lane) a[u] = 0.f;
        long rbase = lb + (long)s * P * NB + (long)(j0 + lane) * NB;
        #pragma unroll
        for (int c4 = 0; c4 < NB; c4 += 8){
          bf16x8 vh, vl;
          #pragma unroll
          for (int u = 0; u < 8; ++u){
            float f = a[c4 + u];
            __bf16 h = (__bf16)f;
            vh[u] = h; vl[u] = (__bf16)(f - (float)h);
          }
          *(bf16x8*)&Lghi[rbase + c4] = vh;
          *(bf16x8*)&Lglo[rbase + c4] = vl;
        }
      }
      loglocal += logf(myp);   // lanes >= NB: myp==1 -> +0
    }
    __syncthreads();

    // ==== phase 3: per-thread fp32 trsm, publish row to Lg (coalesced) ====
    if (tid < q - NB){
      int t = tid;
      float b[NB];
      #pragma unroll
      for (int u = 0; u < NB; ++u) b[u] = Pan[(NB + t) * 33 + u];
      #pragma unroll
      for (int jj = 0; jj < NB; ++jj){
        float acc2 = b[jj];
        for (int u = 0; u < jj; ++u) acc2 -= b[u] * Ld[jj * 33 + u];
        b[jj] = acc2 * Ldr[jj];
      }
      long rbase = lb + (long)s * P * NB + (long)(j0 + NB + t) * NB;
      #pragma unroll
      for (int c4 = 0; c4 < NB; c4 += 8){
        bf16x8 vh, vl;
        #pragma unroll
        for (int u = 0; u < 8; ++u){
          float f = b[c4 + u];
          __bf16 h = (__bf16)f;
          vh[u] = h; vl[u] = (__bf16)(f - (float)h);
        }
        *(bf16x8*)&Lghi[rbase + c4] = vh;
        *(bf16x8*)&Lglo[rbase + c4] = vl;
      }
    }
    __syncthreads();   // Lg visibility (vmcnt drain) + Pan WAR for next step
  }

  // ==== epilogue: reduce logs; publish; last block computes outputs ====
  if (wv == 0){
    float lp = loglocal;
    #pragma unroll
    for (int off = 32; off >= 1; off >>= 1) lp += __shfl_xor(lp, off);
    if (lane == 0){
      __hip_atomic_store(&logdets[mat], lp, __ATOMIC_RELEASE, __HIP_MEMORY_SCOPE_AGENT);
      int old = __hip_atomic_fetch_add(done, 1, __ATOMIC_ACQ_REL, __HIP_MEMORY_SCOPE_AGENT);
      if (old == KC){
        float ld[KC + 1];
        #pragma unroll
        for (int j = 0; j <= KC; ++j)
          ld[j] = __hip_atomic_load(&logdets[j], __ATOMIC_ACQUIRE, __HIP_MEMORY_SCOPE_AGENT);
        out[0] = 0.5f * ld[KC];
        float comp = 0.f;
        for (int j = 0; j < KC; ++j){
          float trPi = (float)counts[j] + 1e-8f;
          comp += ld[j] * trPi / m_tot;
        }
        out[1] = 0.5f * comp;
      }
    }
  }
}

extern "C" void kernel_launch(void* const* d_in, const int* in_sizes, int n_in,
                              void* d_out, int out_size, void* d_ws, size_t ws_size,
                              hipStream_t stream) {
  (void)n_in; (void)out_size; (void)ws_size;
  const float* X = (const float*)d_in[0];
  const int*   Y = (const int*)d_in[1];
  int m = in_sizes[0] / P;     // 16384

  float*  Gk      = (float*)d_ws;                    // 11 * P*P floats
  __bf16* Xhi     = (__bf16*)(Gk + 11L * P * P);     // 512*XT bf16
  __bf16* Xlo     = Xhi + (long)P * XT;              // 512*XT bf16
  int*    colmap  = (int*)(Xlo + (long)P * XT);      // XT ints
  int*    counts  = colmap + XT;                     // 16
  int*    off_pad = counts + 16;                     // 17
  int*    done    = off_pad + 17;                    // 1
  float*  logdets = (float*)(done + 1);              // 16

  // L planes alias the X planes (dead after gram_mfma); 11*P*P <= P*XT
  __bf16* Lghi = Xhi;
  __bf16* Lglo = Xlo;

  sort_k<<<1, 256, 0, stream>>>(Y, colmap, counts, off_pad, done, m);

  dim3 xg(XT / 64, 8);
  xt_k<<<xg, 256, 0, stream>>>(X, colmap, Xhi, Xlo);

  dim3 gg(36, KC);
  gram_mfma<<<gg, 256, 0, stream>>>(Xhi, Xlo, counts, off_pad, Gk);

  sum10_k<<<P * P / 1024, 256, 0, stream>>>(Gk);

  chol_left<<<KC + 1, 1024, 0, stream>>>(Gk, Lghi, Lglo, counts, logdets, done,
                                         (float*)d_out, (float)m);
}